// Round 10
// baseline (650.298 us; speedup 1.0000x reference)
//
#include <hip/hip_runtime.h>
#include <hip/hip_cooperative_groups.h>
#include <hip/hip_bf16.h>

namespace cg = cooperative_groups;

typedef unsigned short USHORT;
typedef long long LL;
typedef short s8v __attribute__((ext_vector_type(8)));
typedef float f32x4 __attribute__((ext_vector_type(4)));

// B=2, L=256, H=512, NH=8, DH=64, MAXLEN=256, PE_ROWS=513
// Dtypes runtime-detected: floats f32-or-bf16 (canonicalized bf16), ints i32-or-i64.
// R10 fix: score task space is 8192 (= 2b x 256i x 16 j-tiles); R8/R9 used 4096 (jt&7),
// leaving j in [128,256) unscored -> the 0.25 absmax. One-line region fix.

__device__ __forceinline__ float bf2f(USHORT u) {
  union { unsigned int i; float f; } v; v.i = ((unsigned int)u) << 16; return v.f;
}
__device__ __forceinline__ USHORT f2bf(float f) {
  unsigned int x = __float_as_uint(f);
  return (USHORT)((x + 0x7fffu + ((x >> 16) & 1u)) >> 16);
}

struct MArgs {
  const void* in[22];
  void* out;
  int* c_seq; int* c_lex; int* c_pos_s; int* c_pos_e;
  USHORT* canon[18];
  USHORT* WrT; USHORT* q_n; USHORT* k_n; USHORT* v_t;
  USHORT* qv_n; USHORT* qu_n; USHORT* wbuf; USHORT* Ptab;
  USHORT* P12; USHORT* P34;
  USHORT* attn; USHORT* out_pre;
  float* S; float* cbv;
};

__device__ __forceinline__ int detect_f(const void* qraw, int t) {
  __shared__ int s_w;
  if (t == 0) s_w = 0;
  __syncthreads();
  const USHORT* qb = (const USHORT*)qraw;
  int wild = 0;
  for (int c = t; c < 512; c += 256) {
    float x = bf2f(qb[c]);
    if (!(fabsf(x) <= 1024.0f)) wild = 1;  // catches NaN too
  }
  if (wild) atomicAdd(&s_w, 1);
  __syncthreads();
  return (s_w == 0) ? 1 : 0;  // 1 iff float inputs are bf16
}

// ---------------- generic MFMA 64x64 tile: C[m][n] = sum_k A[m,k]*W[n,koff+k] (+bias)
struct GD {
  const USHORT* A; const USHORT* W; const USHORT* bias; void* out;
  int M, lda, ldw, koff, ldo, K, obf, trans;
};

__device__ __forceinline__ void gemm_tile(const GD& de, int row0, int col0, int t) {
  const int wave = t >> 6, lane = t & 63;
  const int mrow = row0 + wave * 16 + (lane & 15);
  const int kq = (lane >> 4) * 8;
  const bool mok = (mrow < de.M);
  const USHORT* ar = de.A + (long)(mok ? mrow : row0) * de.lda + kq;
  const int nc = col0 + (lane & 15);
  const USHORT* w0p = de.W + (long)(nc +  0) * de.ldw + de.koff + kq;
  const USHORT* w1p = de.W + (long)(nc + 16) * de.ldw + de.koff + kq;
  const USHORT* w2p = de.W + (long)(nc + 32) * de.ldw + de.koff + kq;
  const USHORT* w3p = de.W + (long)(nc + 48) * de.ldw + de.koff + kq;
  f32x4 acc[4] = {};
#pragma unroll 4
  for (int k0 = 0; k0 < de.K; k0 += 32) {
    s8v av = *(const s8v*)(ar + k0);
    s8v wv0 = *(const s8v*)(w0p + k0);
    s8v wv1 = *(const s8v*)(w1p + k0);
    s8v wv2 = *(const s8v*)(w2p + k0);
    s8v wv3 = *(const s8v*)(w3p + k0);
    acc[0] = __builtin_amdgcn_mfma_f32_16x16x32_bf16(av, wv0, acc[0], 0, 0, 0);
    acc[1] = __builtin_amdgcn_mfma_f32_16x16x32_bf16(av, wv1, acc[1], 0, 0, 0);
    acc[2] = __builtin_amdgcn_mfma_f32_16x16x32_bf16(av, wv2, acc[2], 0, 0, 0);
    acc[3] = __builtin_amdgcn_mfma_f32_16x16x32_bf16(av, wv3, acc[3], 0, 0, 0);
  }
  const int mbase = row0 + wave * 16 + (lane >> 4) * 4;
#pragma unroll
  for (int nt = 0; nt < 4; nt++) {
    const int n = col0 + nt * 16 + (lane & 15);
    const float bias = de.bias ? bf2f(de.bias[n]) : 0.f;
#pragma unroll
    for (int r = 0; r < 4; r++) {
      const int m = mbase + r;
      if (m >= de.M) continue;
      const float vo = acc[nt][r] + bias;
      const long off = de.trans ? ((long)n * de.ldo + m) : ((long)m * de.ldo + n);
      if (de.obf) ((USHORT*)de.out)[off] = f2bf(vo);
      else        ((float*)de.out)[off] = vo;
    }
  }
}

// ---------------- P0: canonicalize + WrT + ints ----------------
__device__ void phase_prep(const MArgs& a, int f, int bid, int gsz, int t) {
  const int ns[18] = {262144,262144,262144,262656,1048576,512,262144,512,262144,512,
                      262144,512,262144,512,262144,512,512,512};
  for (int yi = 0; yi < 18; yi++) {
    if (yi == 12) continue;  // Wr consumed only via WrT
    const int n = ns[yi];
    const USHORT* sb = (const USHORT*)a.in[yi];
    const float* sf = (const float*)a.in[yi];
    USHORT* d = a.canon[yi];
    for (int idx = bid * 256 + t; idx < n; idx += gsz * 256)
      d[idx] = f ? sb[idx] : f2bf(sf[idx]);
  }
  const USHORT* sb = (const USHORT*)a.in[12];
  const float* sf = (const float*)a.in[12];
  for (int idx = bid * 256 + t; idx < 262144; idx += gsz * 256) {
    const int e = idx >> 9, dd = idx & 511;
    const int s = dd * 512 + e;
    a.WrT[idx] = f ? sb[s] : f2bf(sf[s]);  // WrT[e][d] = Wr[d][e]
  }
  if (bid == 0) {
    const int fi = (((const int*)a.in[18])[1] == 0) ? 1 : 0;
    if (t < 2) {
      a.c_seq[t] = fi ? (int)((const LL*)a.in[18])[t] : ((const int*)a.in[18])[t];
      a.c_lex[t] = fi ? (int)((const LL*)a.in[19])[t] : ((const int*)a.in[19])[t];
    }
    for (int c = t; c < 512; c += 256) {
      a.c_pos_s[c] = fi ? (int)((const LL*)a.in[20])[c] : ((const int*)a.in[20])[c];
      a.c_pos_e[c] = fi ? (int)((const LL*)a.in[21])[c] : ((const int*)a.in[21])[c];
    }
  }
}

// ---------------- P1: P tables (bf16, +bf in tbl0), q, k, v^T ----------------
__device__ void phase_g1(const MArgs& a, int bid, int gsz, int t) {
  for (int u = bid; u < 480; u += gsz) {
    GD de; int uy, ux;
    if (u < 288) {
      const int z = u / 72, rem = u % 72; uy = rem / 8; ux = rem % 8;
      de.A = a.canon[3]; de.W = a.canon[4]; de.bias = (z == 0) ? a.canon[5] : nullptr;
      de.out = a.Ptab + (long)z * 513 * 512;
      de.M = 513; de.lda = 512; de.ldw = 2048; de.koff = z * 512; de.ldo = 512;
      de.K = 512; de.obf = 1; de.trans = 0;
    } else {
      const int u2 = u - 288, which = u2 / 64, rem = u2 % 64; uy = rem / 8; ux = rem % 8;
      de.M = 512; de.lda = 512; de.ldw = 512; de.koff = 0; de.ldo = 512;
      de.K = 512; de.obf = 1;
      if (which == 0)      { de.A = a.canon[1]; de.W = a.canon[8];  de.bias = a.canon[9];  de.out = a.q_n; de.trans = 0; }
      else if (which == 1) { de.A = a.canon[0]; de.W = a.canon[6];  de.bias = a.canon[7];  de.out = a.k_n; de.trans = 0; }
      else                 { de.A = a.canon[2]; de.W = a.canon[10]; de.bias = a.canon[11]; de.out = a.v_t; de.trans = 1; }
    }
    gemm_tile(de, uy * 64, ux * 64, t);
  }
}

// ---------------- P2: qv/qu/cbv + P12/P34 pair-table build ----------------
// P12[S][dj] = P1[S] + P2[clamp(S-dj)]; P34[u][dj] = P3[u] + P4[clamp(u-dj)]
__device__ void phase_mid(const MArgs& a, int bid, int gsz, int t) {
  for (int idx = bid * 256 + t; idx < 262144; idx += gsz * 256) {
    const int hd = idx & 511;
    const float qv = bf2f(a.q_n[idx]);
    const float qpv = qv + bf2f(a.canon[17][hd]);
    a.qv_n[idx] = f2bf(qpv);
    a.qu_n[idx] = f2bf(qv + bf2f(a.canon[16][hd]));
    float s = qpv * bf2f(a.canon[13][hd]);
#pragma unroll
    for (int off = 32; off > 0; off >>= 1) s += __shfl_xor(s, off);
    if ((t & 63) == 0) a.cbv[idx >> 6] = s;  // [b,i,h]
  }
  const long TS = 513l * 512;
  for (int r = bid; r < 5130; r += gsz) {
    const int half = (r >= 2565) ? 1 : 0;
    const int rr = half ? (r - 2565) : r;
    const int S0 = rr / 5, dj = rr % 5;
    const USHORT* pa = a.Ptab + (half ? 2 * TS : 0) + (long)S0 * 512;
    const USHORT* pb = a.Ptab + (half ? 3 * TS : TS) + (long)max(S0 - dj, 0) * 512;
    USHORT* to = (half ? a.P34 : a.P12) + (long)rr * 512;
    const int e = t * 2;
    ushort2 xa = *(const ushort2*)(pa + e);
    ushort2 xb = *(const ushort2*)(pb + e);
    ushort2 o;
    o.x = f2bf(bf2f(xa.x) + bf2f(xb.x));
    o.y = f2bf(bf2f(xa.y) + bf2f(xb.y));
    *(ushort2*)(to + e) = o;
  }
}

// ---------------- P3: wproj (bf16) + S_AC (f32, into S) ----------------
__device__ void phase_g2(const MArgs& a, int bid, int gsz, int t) {
  for (int u = bid; u < 768; u += gsz) {
    GD de; int uy, ux;
    if (u < 512) {
      const int z = u / 32, rem = u % 32; ux = rem / 4; uy = rem % 4;
      const int b = z >> 3, h = z & 7;
      de.A = a.qv_n + b * 131072 + h * 64; de.W = a.WrT; de.bias = nullptr;
      de.out = a.wbuf + (long)z * 131072;
      de.M = 256; de.lda = 512; de.ldw = 512; de.koff = h * 64; de.ldo = 512;
      de.K = 64; de.obf = 1; de.trans = 0;
    } else {
      const int u2 = u - 512, z = u2 / 16, rem = u2 % 16; ux = rem / 4; uy = rem % 4;
      const int b = z >> 3, h = z & 7;
      de.A = a.qu_n + b * 131072 + h * 64; de.W = a.k_n + b * 131072 + h * 64; de.bias = nullptr;
      de.out = a.S + (long)z * 65536;
      de.M = 256; de.lda = 512; de.ldw = 512; de.koff = 0; de.ldo = 256;
      de.K = 64; de.obf = 0; de.trans = 0;
    }
    gemm_tile(de, uy * 64, ux * 64, t);
  }
}

// ---------------- P4: score — one wave per (b,i,jt); P12+P34 combine + MFMA --------
// Task space: 2(b) x 256(i) x 16(jt) = 8192.  [R8/R9 bug: used 4096 / jt&7]
__device__ void phase_score(const MArgs& a, int wg, int wstride, int lane) {
  const int n = lane & 15, q = lane >> 4;
  for (int u = wg; u < 8192; u += wstride) {
    const int b = u >> 12, rem = u & 4095, i = rem >> 4, jt = rem & 15;
    int tl = a.c_seq[b] + a.c_lex[b]; tl = min(max(tl, 1), 256);
    const int j0 = jt * 16;
    if (j0 >= tl) continue;
    const int psi = a.c_pos_s[b * 256 + i], pei = a.c_pos_e[b * 256 + i];
    const int j = j0 + n;
    const int psj = a.c_pos_s[b * 256 + j], pej = a.c_pos_e[b * 256 + j];
    const int S0 = min(max(psi - psj + 256, 0), 512);
    const int di = min(max(pei - psi, 0), 4);
    const int dj = min(max(pej - psj, 0), 4);
    const USHORT* p12 = a.P12 + ((long)(S0 * 5 + dj)) * 512 + q * 8;
    const USHORT* p34 = a.P34 + ((long)(min(S0 + di, 512) * 5 + dj)) * 512 + q * 8;
    const USHORT* wr = a.wbuf + ((long)((b * 8 + (n & 7)) * 256 + i)) * 512 + q * 8;
    f32x4 acc = {0.f, 0.f, 0.f, 0.f};
#pragma unroll
    for (int kk = 0; kk < 16; kk++) {
      s8v xa = *(const s8v*)(p12 + kk * 32);
      s8v xb = *(const s8v*)(p34 + kk * 32);
      s8v wv = *(const s8v*)(wr + kk * 32);  // n>=8 duplicates h=n-8; D cols discarded
      s8v af;
#pragma unroll
      for (int x = 0; x < 8; x++) {
        float fs = bf2f((USHORT)xa[x]) + bf2f((USHORT)xb[x]);
        fs = fmaxf(fs, 0.f);
        af[x] = (short)(USHORT)((__float_as_uint(fs) + 0x8000u) >> 16);
      }
      acc = __builtin_amdgcn_mfma_f32_16x16x32_bf16(af, wv, acc, 0, 0, 0);
    }
    if (n < 8) {  // D: col h = lane&15, row j_local = q*4+r; update S in place
      const long base = (long)(b * 8 + n) * 256 + i;
      const float cb = a.cbv[(long)(b * 256 + i) * 8 + n];
      float* dst = a.S + base * 256 + j0 + q * 4;
      const float4 sac = *(const float4*)dst;
      dst[0] = (acc[0] + sac.x + cb) * 0.125f;
      dst[1] = (acc[1] + sac.y + cb) * 0.125f;
      dst[2] = (acc[2] + sac.z + cb) * 0.125f;
      dst[3] = (acc[3] + sac.w + cb) * 0.125f;
    }
  }
}

// ---------------- P5: softmax ----------------
__device__ void phase_softmax(const MArgs& a, int bid, int gsz, int t) {
  __shared__ float red4[4];
  const int lane = t & 63, wave = t >> 6;
  for (int u = bid; u < 512; u += gsz) {
    const int i = u & 255, b = u >> 8;
    int tl = a.c_seq[b] + a.c_lex[b]; tl = min(max(tl, 1), 256);
    for (int h = 0; h < 8; h++) {
      const long base = ((long)(b * 8 + h) * 256 + i) * 256;
      const float val = (t < tl) ? a.S[base + t] : -3.0e38f;
      float m = val;
#pragma unroll
      for (int off = 32; off > 0; off >>= 1) m = fmaxf(m, __shfl_xor(m, off));
      if (lane == 0) red4[wave] = m;
      __syncthreads();
      m = fmaxf(fmaxf(red4[0], red4[1]), fmaxf(red4[2], red4[3]));
      const float pv = (t < tl) ? __expf(val - m) : 0.f;
      float s = pv;
#pragma unroll
      for (int off = 32; off > 0; off >>= 1) s += __shfl_xor(s, off);
      __syncthreads();
      if (lane == 0) red4[wave] = s;
      __syncthreads();
      s = red4[0] + red4[1] + red4[2] + red4[3];
      if (!(s > 1e-30f)) s = 1.f;
      a.attn[base + t] = f2bf(pv / s);
      __syncthreads();
    }
  }
}

// ---------------- P6: attn @ V ----------------
__device__ void phase_av(const MArgs& a, int bid, int gsz, int t) {
  for (int u = bid; u < 64; u += gsz) {
    const int z = u >> 2, uy = u & 3;
    const int b = z >> 3, h = z & 7;
    GD de;
    de.A = a.attn + (long)z * 65536; de.W = a.v_t + (long)(h * 64) * 512 + b * 256;
    de.bias = nullptr; de.out = a.out_pre + b * 131072 + h * 64;
    de.M = 256; de.lda = 256; de.ldw = 512; de.koff = 0; de.ldo = 512;
    de.K = 256; de.obf = 1; de.trans = 0;
    gemm_tile(de, uy * 64, 0, t);
  }
}

// ---------------- P7: final @ Wo^T + bo ----------------
__device__ void phase_final(const MArgs& a, int f, int bid, int gsz, int t) {
  for (int u = bid; u < 64; u += gsz) {
    const int uy = u >> 3, ux = u & 7;
    GD de;
    de.A = a.out_pre; de.W = a.canon[14]; de.bias = a.canon[15]; de.out = a.out;
    de.M = 512; de.lda = 512; de.ldw = 512; de.koff = 0; de.ldo = 512;
    de.K = 512; de.obf = f; de.trans = 0;
    gemm_tile(de, uy * 64, ux * 64, t);
  }
}

// ---------------- cooperative mega-kernel ----------------
__global__ __launch_bounds__(256, 2) void mega_k(MArgs a) {
  const int bid = blockIdx.x, t = threadIdx.x;
  cg::grid_group g = cg::this_grid();
  const int f = detect_f(a.in[1], t);
  phase_prep(a, f, bid, 512, t);
  g.sync();
  phase_g1(a, bid, 512, t);
  g.sync();
  phase_mid(a, bid, 512, t);
  g.sync();
  phase_g2(a, bid, 512, t);
  g.sync();
  phase_score(a, bid * 4 + (t >> 6), 2048, t & 63);
  g.sync();
  phase_softmax(a, bid, 512, t);
  g.sync();
  phase_av(a, bid, 512, t);
  g.sync();
  phase_final(a, f, bid, 512, t);
}

// ---------------- fallback split kernels ----------------
__global__ __launch_bounds__(256) void k_prep(MArgs a)  { phase_prep(a, detect_f(a.in[1], threadIdx.x), blockIdx.x, gridDim.x, threadIdx.x); }
__global__ __launch_bounds__(256) void k_g1(MArgs a)    { phase_g1(a, blockIdx.x, gridDim.x, threadIdx.x); }
__global__ __launch_bounds__(256) void k_mid(MArgs a)   { phase_mid(a, blockIdx.x, gridDim.x, threadIdx.x); }
__global__ __launch_bounds__(256) void k_g2(MArgs a)    { phase_g2(a, blockIdx.x, gridDim.x, threadIdx.x); }
__global__ __launch_bounds__(256) void k_score(MArgs a) { phase_score(a, blockIdx.x * 4 + (threadIdx.x >> 6), gridDim.x * 4, threadIdx.x & 63); }
__global__ __launch_bounds__(256) void k_soft(MArgs a)  { phase_softmax(a, blockIdx.x, gridDim.x, threadIdx.x); }
__global__ __launch_bounds__(256) void k_av(MArgs a)    { phase_av(a, blockIdx.x, gridDim.x, threadIdx.x); }
__global__ __launch_bounds__(256) void k_fin(MArgs a)   { phase_final(a, detect_f(a.in[1], threadIdx.x), blockIdx.x, gridDim.x, threadIdx.x); }

extern "C" void kernel_launch(void* const* d_in, const int* in_sizes, int n_in,
                              void* d_out, int out_size, void* d_ws, size_t ws_size,
                              hipStream_t stream) {
  (void)in_sizes; (void)n_in; (void)out_size; (void)ws_size;

  char* w = (char*)d_ws;
  auto take = [&](size_t n) { char* r = w; w += (n + 255) & ~(size_t)255; return r; };

  MArgs ma;
  for (int i = 0; i < 22; i++) ma.in[i] = d_in[i];
  ma.out = d_out;
  ma.c_seq   = (int*)take(16);
  ma.c_lex   = (int*)take(16);
  ma.c_pos_s = (int*)take(2048);
  ma.c_pos_e = (int*)take(2048);
  const int ns[18] = {262144,262144,262144,262656,1048576,512,262144,512,262144,512,
                      262144,512,262144,512,262144,512,512,512};
  for (int i = 0; i < 18; i++)
    ma.canon[i] = (USHORT*)take(i == 12 ? 512 : (size_t)ns[i] * 2);  // canon[12] unused
  ma.WrT  = (USHORT*)take(262144 * 2);
  ma.q_n  = (USHORT*)take(262144 * 2);
  ma.k_n  = (USHORT*)take(262144 * 2);
  ma.v_t  = (USHORT*)take(262144 * 2);
  ma.qv_n = (USHORT*)take(262144 * 2);
  ma.qu_n = (USHORT*)take(262144 * 2);
  ma.wbuf = (USHORT*)take((size_t)2097152 * 2);
  ma.Ptab = (USHORT*)take((size_t)1050624 * 2);
  ma.P12  = (USHORT*)take((size_t)2565 * 512 * 2);
  ma.P34  = (USHORT*)take((size_t)2565 * 512 * 2);
  ma.S    = (float*)take((size_t)1048576 * 4);
  ma.cbv  = (float*)take(4096 * 4);
  ma.attn    = ma.Ptab;  // overlay: Ptab dead after P2; attn written P5
  ma.out_pre = ma.qv_n;  // overlay: qv_n dead after P3; out_pre written P6

  void* kargs[] = {(void*)&ma};
  hipError_t err = hipLaunchCooperativeKernel(reinterpret_cast<void*>(mega_k),
                                              dim3(512), dim3(256), kargs, 0u, stream);
  if (err != hipSuccess) {
    (void)hipGetLastError();
    k_prep<<<512, 256, 0, stream>>>(ma);
    k_g1<<<480, 256, 0, stream>>>(ma);
    k_mid<<<512, 256, 0, stream>>>(ma);
    k_g2<<<768, 256, 0, stream>>>(ma);
    k_score<<<1024, 256, 0, stream>>>(ma);
    k_soft<<<512, 256, 0, stream>>>(ma);
    k_av<<<64, 256, 0, stream>>>(ma);
    k_fin<<<64, 256, 0, stream>>>(ma);
  }
}

// Round 11
// 226.588 us; speedup vs baseline: 2.8700x; 2.8700x over previous
//
#include <hip/hip_runtime.h>
#include <hip/hip_bf16.h>

typedef unsigned short USHORT;
typedef long long LL;
typedef short s8v __attribute__((ext_vector_type(8)));
typedef float f32x4 __attribute__((ext_vector_type(4)));

// B=2, L=256, H=512, NH=8, DH=64, MAXLEN=256, PE_ROWS=513
// Dtypes runtime-detected: floats f32-or-bf16 (canonicalized bf16), ints i32-or-i64.
// R11: split kernels (grid.sync measured ~60us each on MI355X -> coop dropped),
// P12/P34 factored relu tables, qv/qu eliminated (vwr/uk/cbv side terms), softmax+AV fused.

__device__ __forceinline__ float bf2f(USHORT u) {
  union { unsigned int i; float f; } v; v.i = ((unsigned int)u) << 16; return v.f;
}
__device__ __forceinline__ USHORT f2bf(float f) {
  unsigned int x = __float_as_uint(f);
  return (USHORT)((x + 0x7fffu + ((x >> 16) & 1u)) >> 16);
}

// ---------------- prep: dtype-detect + canonicalize + WrT + ints + flags ----------------
struct PrepArgs {
  const void* fsrc[18]; USHORT* fdst[18]; int fn[18];
  const void* wr_src; USHORT* wrT;
  const void* isrc[4]; int* idst[4];
};

__global__ __launch_bounds__(256) void prep_k(PrepArgs a, const void* qraw, int* flags) {
  __shared__ int s_w;
  const int t = threadIdx.x;
  if (t == 0) s_w = 0;
  __syncthreads();
  const USHORT* qb = (const USHORT*)qraw;
  int wild = 0;
  for (int c = t; c < 512; c += 256) {
    float x = bf2f(qb[c]);
    if (!(fabsf(x) <= 1024.0f)) wild = 1;  // catches NaN too
  }
  if (wild) atomicAdd(&s_w, 1);
  __syncthreads();
  const int f = (s_w == 0) ? 1 : 0;  // 1 iff float inputs are bf16

  const int y = blockIdx.y;
  if (y < 18) {
    const int n = a.fn[y];
    const USHORT* sb = (const USHORT*)a.fsrc[y];
    const float* sf = (const float*)a.fsrc[y];
    USHORT* d = a.fdst[y];
    for (int idx = blockIdx.x * 256 + t; idx < n; idx += gridDim.x * 256)
      d[idx] = f ? sb[idx] : f2bf(sf[idx]);
  } else if (y == 18) {
    const USHORT* sb = (const USHORT*)a.wr_src;
    const float* sf = (const float*)a.wr_src;
    for (int idx = blockIdx.x * 256 + t; idx < 262144; idx += gridDim.x * 256) {
      const int e = idx >> 9, dd = idx & 511;
      const int s = dd * 512 + e;
      a.wrT[idx] = f ? sb[s] : f2bf(sf[s]);  // WrT[e][d] = Wr[d][e]
    }
  } else if (blockIdx.x == 0) {
    if (t == 0) flags[0] = f;
    const int fi = (((const int*)a.isrc[0])[1] == 0) ? 1 : 0;  // seq_len[0] in [100,200)
    if (t < 2) {
      a.idst[0][t] = fi ? (int)((const LL*)a.isrc[0])[t] : ((const int*)a.isrc[0])[t];
      a.idst[1][t] = fi ? (int)((const LL*)a.isrc[1])[t] : ((const int*)a.isrc[1])[t];
    }
    for (int c = t; c < 512; c += 256) {
      a.idst[2][c] = fi ? (int)((const LL*)a.isrc[2])[c] : ((const int*)a.isrc[2])[c];
      a.idst[3][c] = fi ? (int)((const LL*)a.isrc[3])[c] : ((const int*)a.isrc[3])[c];
    }
  }
}

// ---------------- generic multi-desc MFMA GEMM (R7-proven) ----------------
struct GDesc {
  const USHORT* A; const USHORT* W; const USHORT* bias;
  void* out;
  int M, N, K, lda, ldw, koff, ldo, mode, trans, pad;  // mode: 0 f32, 1 bf16, 2 per-flag
};
struct GArgs { GDesc d[32]; };

__global__ __launch_bounds__(256) void gemm2_k(GArgs ga, const int* __restrict__ flags) {
  const GDesc de = ga.d[blockIdx.z];
  const int row0 = blockIdx.y * 64, col0 = blockIdx.x * 64;
  if (row0 >= de.M || col0 >= de.N) return;
  const int wave = threadIdx.x >> 6, lane = threadIdx.x & 63;
  const int mrow = row0 + wave * 16 + (lane & 15);
  const int kq = (lane >> 4) * 8;
  const bool mok = (mrow < de.M);
  const USHORT* ar = de.A + (long)(mok ? mrow : row0) * de.lda + kq;
  const int nc = col0 + (lane & 15);
  const USHORT* w0p = de.W + (long)(nc +  0) * de.ldw + de.koff + kq;
  const USHORT* w1p = de.W + (long)(nc + 16) * de.ldw + de.koff + kq;
  const USHORT* w2p = de.W + (long)(nc + 32) * de.ldw + de.koff + kq;
  const USHORT* w3p = de.W + (long)(nc + 48) * de.ldw + de.koff + kq;

  f32x4 acc[4] = {};
#pragma unroll 4
  for (int k0 = 0; k0 < de.K; k0 += 32) {
    s8v a = *(const s8v*)(ar + k0);
    s8v wv0 = *(const s8v*)(w0p + k0);
    s8v wv1 = *(const s8v*)(w1p + k0);
    s8v wv2 = *(const s8v*)(w2p + k0);
    s8v wv3 = *(const s8v*)(w3p + k0);
    acc[0] = __builtin_amdgcn_mfma_f32_16x16x32_bf16(a, wv0, acc[0], 0, 0, 0);
    acc[1] = __builtin_amdgcn_mfma_f32_16x16x32_bf16(a, wv1, acc[1], 0, 0, 0);
    acc[2] = __builtin_amdgcn_mfma_f32_16x16x32_bf16(a, wv2, acc[2], 0, 0, 0);
    acc[3] = __builtin_amdgcn_mfma_f32_16x16x32_bf16(a, wv3, acc[3], 0, 0, 0);
  }

  const int obf = (de.mode == 2) ? flags[0] : (de.mode == 1);
  const int mbase = row0 + wave * 16 + (lane >> 4) * 4;
#pragma unroll
  for (int nt = 0; nt < 4; nt++) {
    const int n = col0 + nt * 16 + (lane & 15);
    const float bias = de.bias ? bf2f(de.bias[n]) : 0.f;
#pragma unroll
    for (int r = 0; r < 4; r++) {
      const int m = mbase + r;
      if (m >= de.M) continue;
      const float vo = acc[nt][r] + bias;
      const long off = de.trans ? ((long)n * de.ldo + m) : ((long)m * de.ldo + n);
      if (obf) ((USHORT*)de.out)[off] = f2bf(vo);
      else     ((float*)de.out)[off] = vo;
    }
  }
}

// ---------------- mid: P12/P34 pair tables + cbv + uk + vwr ----------------
// P12[S][dj] = P1[S]+P2[clamp(S-dj)]; P34[u][dj] = P3[u]+P4[clamp(u-dj)]
// cbv[b,i,h] = sum_d (q+v)[h,d]*br[h,d];  uk[b,j,h] = sum_d u[h,d]*k[b,j,h,d]
// vwr[h][e]  = sum_d v[h,d]*Wr[h*64+d,e]  (wproj bias)
__global__ __launch_bounds__(256) void mid_k(
    const USHORT* __restrict__ Ptab, const USHORT* __restrict__ q_n,
    const USHORT* __restrict__ k_n, const USHORT* __restrict__ WrT,
    const USHORT* __restrict__ u_bf, const USHORT* __restrict__ v_bf,
    const USHORT* __restrict__ br_bf,
    USHORT* __restrict__ P12, USHORT* __restrict__ P34,
    float* __restrict__ cbv, float* __restrict__ uk, USHORT* __restrict__ vwr)
{
  const int bid = blockIdx.x, t = threadIdx.x, gsz = gridDim.x;
  const long TS = 513l * 512;
  for (int r = bid; r < 5130; r += gsz) {
    const int half = (r >= 2565) ? 1 : 0;
    const int rr = half ? (r - 2565) : r;
    const int S0 = rr / 5, dj = rr % 5;
    const USHORT* pa = Ptab + (half ? 2 * TS : 0) + (long)S0 * 512;
    const USHORT* pb = Ptab + (half ? 3 * TS : TS) + (long)max(S0 - dj, 0) * 512;
    USHORT* to = (half ? P34 : P12) + (long)rr * 512;
    const int e = t * 2;
    ushort2 xa = *(const ushort2*)(pa + e);
    ushort2 xb = *(const ushort2*)(pb + e);
    ushort2 o;
    o.x = f2bf(bf2f(xa.x) + bf2f(xb.x));
    o.y = f2bf(bf2f(xa.y) + bf2f(xb.y));
    *(ushort2*)(to + e) = o;
  }
  for (int idx = bid * 256 + t; idx < 262144; idx += gsz * 256) {
    const int hd = idx & 511;
    float s = (bf2f(q_n[idx]) + bf2f(v_bf[hd])) * bf2f(br_bf[hd]);
    float s2 = bf2f(k_n[idx]) * bf2f(u_bf[hd]);
#pragma unroll
    for (int off = 32; off > 0; off >>= 1) { s += __shfl_xor(s, off); s2 += __shfl_xor(s2, off); }
    if ((t & 63) == 0) { cbv[idx >> 6] = s; uk[idx >> 6] = s2; }
  }
  for (int o = bid * 256 + t; o < 4096; o += gsz * 256) {
    const int h = o >> 9, e = o & 511;
    float s = 0.f;
    const USHORT* wrow = WrT + (long)e * 512 + h * 64;
    const USHORT* vrow = v_bf + h * 64;
#pragma unroll
    for (int d = 0; d < 64; d += 4) {
      ushort4 wv = *(const ushort4*)(wrow + d);
      ushort4 vv = *(const ushort4*)(vrow + d);
      s += bf2f(vv.x) * bf2f(wv.x) + bf2f(vv.y) * bf2f(wv.y) +
           bf2f(vv.z) * bf2f(wv.z) + bf2f(vv.w) * bf2f(wv.w);
    }
    vwr[o] = f2bf(s);  // vwr[h*512+e]
  }
}

// ---------------- score: one wave per (b,i,jt) [jt in 0..16) via z*2+wave] ----------------
__global__ __launch_bounds__(128) void score4_k(
    const USHORT* __restrict__ P12, const USHORT* __restrict__ P34,
    const float* __restrict__ cbv, const float* __restrict__ uk,
    const USHORT* __restrict__ wbuf,
    const int* __restrict__ seq_len, const int* __restrict__ lex_num,
    const int* __restrict__ pos_s, const int* __restrict__ pos_e,
    float* __restrict__ S)
{
  const int i = blockIdx.x, b = blockIdx.y;
  const int wave = threadIdx.x >> 6, lane = threadIdx.x & 63;
  const int jt = blockIdx.z * 2 + wave;
  int tl = seq_len[b] + lex_num[b];
  tl = min(max(tl, 1), 256);
  const int j0 = jt * 16;
  if (j0 >= tl) return;
  const int n = lane & 15, q = lane >> 4;
  const int psi = pos_s[b * 256 + i], pei = pos_e[b * 256 + i];
  const int j = j0 + n;
  const int psj = pos_s[b * 256 + j], pej = pos_e[b * 256 + j];
  const int S0 = min(max(psi - psj + 256, 0), 512);
  const int di = min(max(pei - psi, 0), 4);
  const int dj = min(max(pej - psj, 0), 4);
  const USHORT* p12 = P12 + ((long)(S0 * 5 + dj)) * 512 + q * 8;
  const USHORT* p34 = P34 + ((long)(min(S0 + di, 512) * 5 + dj)) * 512 + q * 8;
  const USHORT* wr = wbuf + ((long)((b * 8 + (n & 7)) * 256 + i)) * 512 + q * 8;

  f32x4 acc = {0.f, 0.f, 0.f, 0.f};
#pragma unroll
  for (int kk = 0; kk < 16; kk++) {
    s8v xa = *(const s8v*)(p12 + kk * 32);
    s8v xb = *(const s8v*)(p34 + kk * 32);
    s8v wv = *(const s8v*)(wr + kk * 32);  // n>=8 duplicates h=n-8; D cols discarded
    s8v af;
#pragma unroll
    for (int x = 0; x < 8; x++) {
      float fs = bf2f((USHORT)xa[x]) + bf2f((USHORT)xb[x]);
      fs = fmaxf(fs, 0.f);
      af[x] = (short)(USHORT)((__float_as_uint(fs) + 0x8000u) >> 16);
    }
    acc = __builtin_amdgcn_mfma_f32_16x16x32_bf16(af, wv, acc, 0, 0, 0);
  }
  if (n < 8) {  // D: col h = lane&15, row j_local = q*4+r; S updated in place
    const long base = (long)(b * 8 + n) * 256 + i;
    const float cb = cbv[(long)(b * 256 + i) * 8 + n];
    float* dst = S + base * 256 + j0 + q * 4;
    const float4 sac = *(const float4*)dst;
    const float* sacp = (const float*)&sac;
#pragma unroll
    for (int r = 0; r < 4; r++) {
      const int jr = j0 + q * 4 + r;
      dst[r] = (acc[r] + sacp[r] + cb + uk[(long)(b * 256 + jr) * 8 + n]) * 0.125f;
    }
  }
}

// ---------------- softmax + attn@V fused: one block per (b,i) ----------------
__global__ __launch_bounds__(256) void softav_k(
    const float* __restrict__ S, const USHORT* __restrict__ v_t,
    const int* __restrict__ seq_len, const int* __restrict__ lex_num,
    USHORT* __restrict__ out_pre)
{
  __shared__ float att[8 * 256];
  __shared__ float red4[4];
  const int i = blockIdx.x, b = blockIdx.y, t = threadIdx.x;
  const int lane = t & 63, wave = t >> 6;
  int tl = seq_len[b] + lex_num[b];
  tl = min(max(tl, 1), 256);
  for (int h = 0; h < 8; h++) {
    const long base = ((long)(b * 8 + h) * 256 + i) * 256;
    const float val = (t < tl) ? S[base + t] : -3.0e38f;
    float m = val;
#pragma unroll
    for (int off = 32; off > 0; off >>= 1) m = fmaxf(m, __shfl_xor(m, off));
    if (lane == 0) red4[wave] = m;
    __syncthreads();
    m = fmaxf(fmaxf(red4[0], red4[1]), fmaxf(red4[2], red4[3]));
    const float pv = (t < tl) ? __expf(val - m) : 0.f;
    float s = pv;
#pragma unroll
    for (int off = 32; off > 0; off >>= 1) s += __shfl_xor(s, off);
    __syncthreads();
    if (lane == 0) red4[wave] = s;
    __syncthreads();
    s = red4[0] + red4[1] + red4[2] + red4[3];
    if (!(s > 1e-30f)) s = 1.f;
    att[h * 256 + t] = pv / s;
    __syncthreads();
  }
  // attn @ V: thread (h,d) dots att row with contiguous v_t row
#pragma unroll
  for (int pass = 0; pass < 2; pass++) {
    const int h = (t >> 6) + 4 * pass;
    const int d = t & 63;
    const USHORT* vrow = v_t + (long)(h * 64 + d) * 512 + b * 256;
    const float* arow = &att[h * 256];
    float acc = 0.f;
    const int tl4 = (tl + 3) & ~3;
    for (int jj = 0; jj < tl4; jj += 4) {
      ushort4 vv = *(const ushort4*)(vrow + jj);
      acc += arow[jj + 0] * bf2f(vv.x) + arow[jj + 1] * bf2f(vv.y) +
             arow[jj + 2] * bf2f(vv.z) + arow[jj + 3] * bf2f(vv.w);
    }
    out_pre[(long)(b * 256 + i) * 512 + h * 64 + d] = f2bf(acc);
  }
}

extern "C" void kernel_launch(void* const* d_in, const int* in_sizes, int n_in,
                              void* d_out, int out_size, void* d_ws, size_t ws_size,
                              hipStream_t stream) {
  (void)in_sizes; (void)n_in; (void)out_size; (void)ws_size;

  char* w = (char*)d_ws;
  auto take = [&](size_t n) { char* r = w; w += (n + 255) & ~(size_t)255; return r; };

  int* flags   = (int*)take(16);
  int* c_seq   = (int*)take(16);
  int* c_lex   = (int*)take(16);
  int* c_pos_s = (int*)take(2048);
  int* c_pos_e = (int*)take(2048);
  const int ns[18] = {262144,262144,262144,262656,1048576,512,262144,512,262144,512,
                      262144,512,262144,512,262144,512,512,512};
  USHORT* canon[18];
  for (int i = 0; i < 18; i++) canon[i] = (USHORT*)take((size_t)ns[i] * 2);
  USHORT* WrT     = (USHORT*)take((size_t)262144 * 2);
  USHORT* q_n     = (USHORT*)take((size_t)262144 * 2);
  USHORT* k_n     = (USHORT*)take((size_t)262144 * 2);
  USHORT* v_t     = (USHORT*)take((size_t)262144 * 2);
  USHORT* wbuf    = (USHORT*)take((size_t)2097152 * 2);
  USHORT* Ptab    = (USHORT*)take((size_t)1050624 * 2);
  USHORT* P12     = (USHORT*)take((size_t)2565 * 512 * 2);
  USHORT* P34     = (USHORT*)take((size_t)2565 * 512 * 2);
  USHORT* vwr     = (USHORT*)take((size_t)4096 * 2);
  USHORT* out_pre = (USHORT*)take((size_t)262144 * 2);
  float* S   = (float*)take((size_t)1048576 * 4);
  float* cbv = (float*)take((size_t)4096 * 4);
  float* uk  = (float*)take((size_t)4096 * 4);

  // 1) prep
  PrepArgs pa;
  for (int i = 0; i < 18; i++) { pa.fsrc[i] = d_in[i]; pa.fdst[i] = canon[i]; pa.fn[i] = ns[i]; }
  pa.wr_src = d_in[12]; pa.wrT = WrT;
  for (int i = 0; i < 4; i++) pa.isrc[i] = d_in[18 + i];
  pa.idst[0] = c_seq; pa.idst[1] = c_lex; pa.idst[2] = c_pos_s; pa.idst[3] = c_pos_e;
  prep_k<<<dim3(64, 20), 256, 0, stream>>>(pa, d_in[1], flags);

  // 2) g1: P tables (bf16, +bf in tbl0) + q/k (bf16) + v (bf16, transposed)
  GArgs gA = {};
  for (int z = 0; z < 4; z++)
    gA.d[z] = {canon[3], canon[4], (z == 0) ? canon[5] : nullptr, Ptab + (long)z * 513 * 512,
               513, 512, 512, 512, 2048, z * 512, 512, 1, 0, 0};
  gA.d[4] = {canon[1], canon[8],  canon[9],  q_n, 512, 512, 512, 512, 512, 0, 512, 1, 0, 0};
  gA.d[5] = {canon[0], canon[6],  canon[7],  k_n, 512, 512, 512, 512, 512, 0, 512, 1, 0, 0};
  gA.d[6] = {canon[2], canon[10], canon[11], v_t, 512, 512, 512, 512, 512, 0, 512, 1, 1, 0};
  gemm2_k<<<dim3(8, 9, 7), 256, 0, stream>>>(gA, flags);

  // 3) mid: P12/P34 + cbv + uk + vwr
  mid_k<<<512, 256, 0, stream>>>(Ptab, q_n, k_n, WrT, canon[16], canon[17], canon[13],
                                 P12, P34, cbv, uk, vwr);

  // 4) g2: wproj (q@WrT + vwr bias, bf16) + S_AC (q@k^T, f32 into S)
  GArgs gB = {};
  for (int z = 0; z < 16; z++) {
    const int b = z >> 3, h = z & 7;
    gB.d[z] = {q_n + b * 131072 + h * 64, WrT, vwr + h * 512, wbuf + (long)z * 131072,
               256, 512, 64, 512, 512, h * 64, 512, 1, 0, 0};
  }
  for (int z = 0; z < 16; z++) {
    const int b = z >> 3, h = z & 7;
    gB.d[16 + z] = {q_n + b * 131072 + h * 64, k_n + b * 131072 + h * 64, nullptr,
                    S + (long)z * 65536, 256, 256, 64, 512, 512, 0, 256, 0, 0, 0};
  }
  gemm2_k<<<dim3(8, 4, 32), 256, 0, stream>>>(gB, flags);

  // 5) score -> S in place
  score4_k<<<dim3(256, 2, 8), 128, 0, stream>>>(
      P12, P34, cbv, uk, wbuf, c_seq, c_lex, c_pos_s, c_pos_e, S);

  // 6) softmax + attn@V -> out_pre (bf16)
  softav_k<<<dim3(256, 2), 256, 0, stream>>>(S, v_t, c_seq, c_lex, out_pre);

  // 7) final: out = out_pre @ Wo.T + bo -> d_out (dtype per flag)
  GArgs gC = {};
  gC.d[0] = {out_pre, canon[14], canon[15], d_out, 512, 512, 512, 512, 512, 0, 512, 2, 0, 0};
  gemm2_k<<<dim3(8, 8, 1), 256, 0, stream>>>(gC, flags);
}

// Round 12
// 223.163 us; speedup vs baseline: 2.9140x; 1.0154x over previous
//
#include <hip/hip_runtime.h>
#include <hip/hip_bf16.h>

typedef unsigned short USHORT;
typedef long long LL;
typedef short s8v __attribute__((ext_vector_type(8)));
typedef float f32x4 __attribute__((ext_vector_type(4)));

// B=2, L=256, H=512, NH=8, DH=64, MAXLEN=256, PE_ROWS=513
// Dtypes runtime-detected: floats f32-or-bf16 (canonicalized bf16), ints i32-or-i64.
// R12: full relu T-table (12825 x 512 bf16) built in mid_k; score = 2 loads + MFMA per kk.

__device__ __forceinline__ float bf2f(USHORT u) {
  union { unsigned int i; float f; } v; v.i = ((unsigned int)u) << 16; return v.f;
}
__device__ __forceinline__ USHORT f2bf(float f) {
  unsigned int x = __float_as_uint(f);
  return (USHORT)((x + 0x7fffu + ((x >> 16) & 1u)) >> 16);
}

// ---------------- prep: dtype-detect + canonicalize + WrT + ints + flags ----------------
struct PrepArgs {
  const void* fsrc[18]; USHORT* fdst[18]; int fn[18];
  const void* wr_src; USHORT* wrT;
  const void* isrc[4]; int* idst[4];
};

__global__ __launch_bounds__(256) void prep_k(PrepArgs a, const void* qraw, int* flags) {
  __shared__ int s_w;
  const int t = threadIdx.x;
  if (t == 0) s_w = 0;
  __syncthreads();
  const USHORT* qb = (const USHORT*)qraw;
  int wild = 0;
  for (int c = t; c < 512; c += 256) {
    float x = bf2f(qb[c]);
    if (!(fabsf(x) <= 1024.0f)) wild = 1;  // catches NaN too
  }
  if (wild) atomicAdd(&s_w, 1);
  __syncthreads();
  const int f = (s_w == 0) ? 1 : 0;  // 1 iff float inputs are bf16

  const int y = blockIdx.y;
  if (y < 18) {
    const int n = a.fn[y];
    const USHORT* sb = (const USHORT*)a.fsrc[y];
    const float* sf = (const float*)a.fsrc[y];
    USHORT* d = a.fdst[y];
    for (int idx = blockIdx.x * 256 + t; idx < n; idx += gridDim.x * 256)
      d[idx] = f ? sb[idx] : f2bf(sf[idx]);
  } else if (y == 18) {
    const USHORT* sb = (const USHORT*)a.wr_src;
    const float* sf = (const float*)a.wr_src;
    for (int idx = blockIdx.x * 256 + t; idx < 262144; idx += gridDim.x * 256) {
      const int e = idx >> 9, dd = idx & 511;
      const int s = dd * 512 + e;
      a.wrT[idx] = f ? sb[s] : f2bf(sf[s]);  // WrT[e][d] = Wr[d][e]
    }
  } else if (blockIdx.x == 0) {
    if (t == 0) flags[0] = f;
    const int fi = (((const int*)a.isrc[0])[1] == 0) ? 1 : 0;  // seq_len[0] in [100,200)
    if (t < 2) {
      a.idst[0][t] = fi ? (int)((const LL*)a.isrc[0])[t] : ((const int*)a.isrc[0])[t];
      a.idst[1][t] = fi ? (int)((const LL*)a.isrc[1])[t] : ((const int*)a.isrc[1])[t];
    }
    for (int c = t; c < 512; c += 256) {
      a.idst[2][c] = fi ? (int)((const LL*)a.isrc[2])[c] : ((const int*)a.isrc[2])[c];
      a.idst[3][c] = fi ? (int)((const LL*)a.isrc[3])[c] : ((const int*)a.isrc[3])[c];
    }
  }
}

// ---------------- generic multi-desc MFMA GEMM (R7-proven) ----------------
struct GDesc {
  const USHORT* A; const USHORT* W; const USHORT* bias;
  void* out;
  int M, N, K, lda, ldw, koff, ldo, mode, trans, pad;  // mode: 0 f32, 1 bf16, 2 per-flag
};
struct GArgs { GDesc d[32]; };

__global__ __launch_bounds__(256) void gemm2_k(GArgs ga, const int* __restrict__ flags) {
  const GDesc de = ga.d[blockIdx.z];
  const int row0 = blockIdx.y * 64, col0 = blockIdx.x * 64;
  if (row0 >= de.M || col0 >= de.N) return;
  const int wave = threadIdx.x >> 6, lane = threadIdx.x & 63;
  const int mrow = row0 + wave * 16 + (lane & 15);
  const int kq = (lane >> 4) * 8;
  const bool mok = (mrow < de.M);
  const USHORT* ar = de.A + (long)(mok ? mrow : row0) * de.lda + kq;
  const int nc = col0 + (lane & 15);
  const USHORT* w0p = de.W + (long)(nc +  0) * de.ldw + de.koff + kq;
  const USHORT* w1p = de.W + (long)(nc + 16) * de.ldw + de.koff + kq;
  const USHORT* w2p = de.W + (long)(nc + 32) * de.ldw + de.koff + kq;
  const USHORT* w3p = de.W + (long)(nc + 48) * de.ldw + de.koff + kq;

  f32x4 acc[4] = {};
#pragma unroll 4
  for (int k0 = 0; k0 < de.K; k0 += 32) {
    s8v a = *(const s8v*)(ar + k0);
    s8v wv0 = *(const s8v*)(w0p + k0);
    s8v wv1 = *(const s8v*)(w1p + k0);
    s8v wv2 = *(const s8v*)(w2p + k0);
    s8v wv3 = *(const s8v*)(w3p + k0);
    acc[0] = __builtin_amdgcn_mfma_f32_16x16x32_bf16(a, wv0, acc[0], 0, 0, 0);
    acc[1] = __builtin_amdgcn_mfma_f32_16x16x32_bf16(a, wv1, acc[1], 0, 0, 0);
    acc[2] = __builtin_amdgcn_mfma_f32_16x16x32_bf16(a, wv2, acc[2], 0, 0, 0);
    acc[3] = __builtin_amdgcn_mfma_f32_16x16x32_bf16(a, wv3, acc[3], 0, 0, 0);
  }

  const int obf = (de.mode == 2) ? flags[0] : (de.mode == 1);
  const int mbase = row0 + wave * 16 + (lane >> 4) * 4;
#pragma unroll
  for (int nt = 0; nt < 4; nt++) {
    const int n = col0 + nt * 16 + (lane & 15);
    const float bias = de.bias ? bf2f(de.bias[n]) : 0.f;
#pragma unroll
    for (int r = 0; r < 4; r++) {
      const int m = mbase + r;
      if (m >= de.M) continue;
      const float vo = acc[nt][r] + bias;
      const long off = de.trans ? ((long)n * de.ldo + m) : ((long)m * de.ldo + n);
      if (obf) ((USHORT*)de.out)[off] = f2bf(vo);
      else     ((float*)de.out)[off] = vo;
    }
  }
}

// ---------------- mid: full relu T-table + cbv + uk + vwr ----------------
// T[(S0*25+di*5+dj)][e] = relu(P1[S0]+P2[S0-dj]+P3[S0+di]+P4[S0+di-dj])[e]
// cbv[b,i,h] = sum_d (q+v)[h,d]*br[h,d];  uk[b,j,h] = sum_d u[h,d]*k[b,j,h,d]
// vwr[h][e]  = sum_d v[h,d]*Wr[h*64+d,e]  (wproj bias)
__global__ __launch_bounds__(256) void mid_k(
    const USHORT* __restrict__ Ptab, const USHORT* __restrict__ q_n,
    const USHORT* __restrict__ k_n, const USHORT* __restrict__ WrT,
    const USHORT* __restrict__ u_bf, const USHORT* __restrict__ v_bf,
    const USHORT* __restrict__ br_bf,
    USHORT* __restrict__ T,
    float* __restrict__ cbv, float* __restrict__ uk, USHORT* __restrict__ vwr)
{
  const int bid = blockIdx.x, t = threadIdx.x, gsz = gridDim.x;
  const long TS = 513l * 512;
  for (int r = bid; r < 12825; r += gsz) {
    const int S0 = r / 25, rem = r % 25, di = rem / 5, dj = rem % 5;
    const USHORT* p1 = Ptab + (long)S0 * 512;
    const USHORT* p2 = Ptab + TS + (long)max(S0 - dj, 0) * 512;
    const USHORT* p3 = Ptab + 2 * TS + (long)min(S0 + di, 512) * 512;
    const USHORT* p4 = Ptab + 3 * TS + (long)min(max(S0 + di - dj, 0), 512) * 512;
    USHORT* to = T + (long)r * 512;
    const int e = t * 2;
    ushort2 x1 = *(const ushort2*)(p1 + e);
    ushort2 x2 = *(const ushort2*)(p2 + e);
    ushort2 x3 = *(const ushort2*)(p3 + e);
    ushort2 x4 = *(const ushort2*)(p4 + e);
    ushort2 o;
    o.x = f2bf(fmaxf(bf2f(x1.x) + bf2f(x2.x) + bf2f(x3.x) + bf2f(x4.x), 0.f));
    o.y = f2bf(fmaxf(bf2f(x1.y) + bf2f(x2.y) + bf2f(x3.y) + bf2f(x4.y), 0.f));
    *(ushort2*)(to + e) = o;
  }
  for (int idx = bid * 256 + t; idx < 262144; idx += gsz * 256) {
    const int hd = idx & 511;
    float s = (bf2f(q_n[idx]) + bf2f(v_bf[hd])) * bf2f(br_bf[hd]);
    float s2 = bf2f(k_n[idx]) * bf2f(u_bf[hd]);
#pragma unroll
    for (int off = 32; off > 0; off >>= 1) { s += __shfl_xor(s, off); s2 += __shfl_xor(s2, off); }
    if ((t & 63) == 0) { cbv[idx >> 6] = s; uk[idx >> 6] = s2; }
  }
  for (int o = bid * 256 + t; o < 4096; o += gsz * 256) {
    const int h = o >> 9, e = o & 511;
    float s = 0.f;
    const USHORT* wrow = WrT + (long)e * 512 + h * 64;
    const USHORT* vrow = v_bf + h * 64;
#pragma unroll
    for (int d = 0; d < 64; d += 4) {
      ushort4 wv = *(const ushort4*)(wrow + d);
      ushort4 vv = *(const ushort4*)(vrow + d);
      s += bf2f(vv.x) * bf2f(wv.x) + bf2f(vv.y) * bf2f(wv.y) +
           bf2f(vv.z) * bf2f(wv.z) + bf2f(vv.w) * bf2f(wv.w);
    }
    vwr[o] = f2bf(s);  // vwr[h*512+e]
  }
}

// ---------------- score: one wave per (b,i,jt), jt = z*4+wave; 2 loads + MFMA per kk ----
__global__ __launch_bounds__(256) void score5_k(
    const USHORT* __restrict__ T,
    const float* __restrict__ cbv, const float* __restrict__ uk,
    const USHORT* __restrict__ wbuf,
    const int* __restrict__ seq_len, const int* __restrict__ lex_num,
    const int* __restrict__ pos_s, const int* __restrict__ pos_e,
    float* __restrict__ S)
{
  const int i = blockIdx.x, b = blockIdx.y;
  const int wave = threadIdx.x >> 6, lane = threadIdx.x & 63;
  const int jt = blockIdx.z * 4 + wave;
  int tl = seq_len[b] + lex_num[b];
  tl = min(max(tl, 1), 256);
  const int j0 = jt * 16;
  if (j0 >= tl) return;
  const int n = lane & 15, q = lane >> 4;
  const int psi = pos_s[b * 256 + i], pei = pos_e[b * 256 + i];
  const int j = j0 + n;
  const int psj = pos_s[b * 256 + j], pej = pos_e[b * 256 + j];
  const int S0 = min(max(psi - psj + 256, 0), 512);
  const int di = min(max(pei - psi, 0), 4);
  const int dj = min(max(pej - psj, 0), 4);
  const USHORT* tp = T + ((long)(S0 * 25 + di * 5 + dj)) * 512 + q * 8;
  const USHORT* wr = wbuf + ((long)((b * 8 + (n & 7)) * 256 + i)) * 512 + q * 8;

  f32x4 acc = {0.f, 0.f, 0.f, 0.f};
#pragma unroll
  for (int kk = 0; kk < 16; kk++) {
    s8v av = *(const s8v*)(tp + kk * 32);
    s8v wv = *(const s8v*)(wr + kk * 32);  // n>=8 duplicates h=n-8; D cols discarded
    acc = __builtin_amdgcn_mfma_f32_16x16x32_bf16(av, wv, acc, 0, 0, 0);
  }
  if (n < 8) {  // D: col h = lane&15, row j_local = q*4+r; S updated in place
    const long base = (long)(b * 8 + n) * 256 + i;
    const float cb = cbv[(long)(b * 256 + i) * 8 + n];
    float* dst = S + base * 256 + j0 + q * 4;
    const float4 sac = *(const float4*)dst;
    const float* sacp = (const float*)&sac;
#pragma unroll
    for (int r = 0; r < 4; r++) {
      const int jr = j0 + q * 4 + r;
      dst[r] = (acc[r] + sacp[r] + cb + uk[(long)(b * 256 + jr) * 8 + n]) * 0.125f;
    }
  }
}

// ---------------- softmax + attn@V fused: one block per (b,i) ----------------
__global__ __launch_bounds__(256) void softav_k(
    const float* __restrict__ S, const USHORT* __restrict__ v_t,
    const int* __restrict__ seq_len, const int* __restrict__ lex_num,
    USHORT* __restrict__ out_pre)
{
  __shared__ float att[8 * 256];
  __shared__ float red4[4];
  const int i = blockIdx.x, b = blockIdx.y, t = threadIdx.x;
  const int lane = t & 63, wave = t >> 6;
  int tl = seq_len[b] + lex_num[b];
  tl = min(max(tl, 1), 256);
  for (int h = 0; h < 8; h++) {
    const long base = ((long)(b * 8 + h) * 256 + i) * 256;
    const float val = (t < tl) ? S[base + t] : -3.0e38f;
    float m = val;
#pragma unroll
    for (int off = 32; off > 0; off >>= 1) m = fmaxf(m, __shfl_xor(m, off));
    if (lane == 0) red4[wave] = m;
    __syncthreads();
    m = fmaxf(fmaxf(red4[0], red4[1]), fmaxf(red4[2], red4[3]));
    const float pv = (t < tl) ? __expf(val - m) : 0.f;
    float s = pv;
#pragma unroll
    for (int off = 32; off > 0; off >>= 1) s += __shfl_xor(s, off);
    __syncthreads();
    if (lane == 0) red4[wave] = s;
    __syncthreads();
    s = red4[0] + red4[1] + red4[2] + red4[3];
    if (!(s > 1e-30f)) s = 1.f;
    att[h * 256 + t] = pv / s;
    __syncthreads();
  }
  // attn @ V: thread (h,d) dots att row with contiguous v_t row
#pragma unroll
  for (int pass = 0; pass < 2; pass++) {
    const int h = (t >> 6) + 4 * pass;
    const int d = t & 63;
    const USHORT* vrow = v_t + (long)(h * 64 + d) * 512 + b * 256;
    const float* arow = &att[h * 256];
    float acc = 0.f;
    const int tl4 = (tl + 3) & ~3;
    for (int jj = 0; jj < tl4; jj += 4) {
      ushort4 vv = *(const ushort4*)(vrow + jj);
      acc += arow[jj + 0] * bf2f(vv.x) + arow[jj + 1] * bf2f(vv.y) +
             arow[jj + 2] * bf2f(vv.z) + arow[jj + 3] * bf2f(vv.w);
    }
    out_pre[(long)(b * 256 + i) * 512 + h * 64 + d] = f2bf(acc);
  }
}

extern "C" void kernel_launch(void* const* d_in, const int* in_sizes, int n_in,
                              void* d_out, int out_size, void* d_ws, size_t ws_size,
                              hipStream_t stream) {
  (void)in_sizes; (void)n_in; (void)out_size; (void)ws_size;

  char* w = (char*)d_ws;
  auto take = [&](size_t n) { char* r = w; w += (n + 255) & ~(size_t)255; return r; };

  int* flags   = (int*)take(16);
  int* c_seq   = (int*)take(16);
  int* c_lex   = (int*)take(16);
  int* c_pos_s = (int*)take(2048);
  int* c_pos_e = (int*)take(2048);
  const int ns[18] = {262144,262144,262144,262656,1048576,512,262144,512,262144,512,
                      262144,512,262144,512,262144,512,512,512};
  USHORT* canon[18];
  for (int i = 0; i < 18; i++) canon[i] = (USHORT*)take((size_t)ns[i] * 2);
  USHORT* WrT     = (USHORT*)take((size_t)262144 * 2);
  USHORT* q_n     = (USHORT*)take((size_t)262144 * 2);
  USHORT* k_n     = (USHORT*)take((size_t)262144 * 2);
  USHORT* v_t     = (USHORT*)take((size_t)262144 * 2);
  USHORT* wbuf    = (USHORT*)take((size_t)2097152 * 2);
  USHORT* Ptab    = (USHORT*)take((size_t)1050624 * 2);
  USHORT* T       = (USHORT*)take((size_t)12825 * 512 * 2);
  USHORT* vwr     = (USHORT*)take((size_t)4096 * 2);
  USHORT* out_pre = (USHORT*)take((size_t)262144 * 2);
  float* S   = (float*)take((size_t)1048576 * 4);
  float* cbv = (float*)take((size_t)4096 * 4);
  float* uk  = (float*)take((size_t)4096 * 4);

  // 1) prep
  PrepArgs pa;
  for (int i = 0; i < 18; i++) { pa.fsrc[i] = d_in[i]; pa.fdst[i] = canon[i]; pa.fn[i] = ns[i]; }
  pa.wr_src = d_in[12]; pa.wrT = WrT;
  for (int i = 0; i < 4; i++) pa.isrc[i] = d_in[18 + i];
  pa.idst[0] = c_seq; pa.idst[1] = c_lex; pa.idst[2] = c_pos_s; pa.idst[3] = c_pos_e;
  prep_k<<<dim3(64, 20), 256, 0, stream>>>(pa, d_in[1], flags);

  // 2) g1: P tables (bf16, +bf in tbl0) + q/k (bf16) + v (bf16, transposed)
  GArgs gA = {};
  for (int z = 0; z < 4; z++)
    gA.d[z] = {canon[3], canon[4], (z == 0) ? canon[5] : nullptr, Ptab + (long)z * 513 * 512,
               513, 512, 512, 512, 2048, z * 512, 512, 1, 0, 0};
  gA.d[4] = {canon[1], canon[8],  canon[9],  q_n, 512, 512, 512, 512, 512, 0, 512, 1, 0, 0};
  gA.d[5] = {canon[0], canon[6],  canon[7],  k_n, 512, 512, 512, 512, 512, 0, 512, 1, 0, 0};
  gA.d[6] = {canon[2], canon[10], canon[11], v_t, 512, 512, 512, 512, 512, 0, 512, 1, 1, 0};
  gemm2_k<<<dim3(8, 9, 7), 256, 0, stream>>>(gA, flags);

  // 3) mid: T table + cbv + uk + vwr
  mid_k<<<512, 256, 0, stream>>>(Ptab, q_n, k_n, WrT, canon[16], canon[17], canon[13],
                                 T, cbv, uk, vwr);

  // 4) g2: wproj (q@WrT + vwr bias, bf16) + S_AC (q@k^T, f32 into S)
  GArgs gB = {};
  for (int z = 0; z < 16; z++) {
    const int b = z >> 3, h = z & 7;
    gB.d[z] = {q_n + b * 131072 + h * 64, WrT, vwr + h * 512, wbuf + (long)z * 131072,
               256, 512, 64, 512, 512, h * 64, 512, 1, 0, 0};
  }
  for (int z = 0; z < 16; z++) {
    const int b = z >> 3, h = z & 7;
    gB.d[16 + z] = {q_n + b * 131072 + h * 64, k_n + b * 131072 + h * 64, nullptr,
                    S + (long)z * 65536, 256, 256, 64, 512, 512, 0, 256, 0, 0, 0};
  }
  gemm2_k<<<dim3(8, 4, 32), 256, 0, stream>>>(gB, flags);

  // 5) score -> S in place
  score5_k<<<dim3(256, 2, 4), 256, 0, stream>>>(
      T, cbv, uk, wbuf, c_seq, c_lex, c_pos_s, c_pos_e, S);

  // 6) softmax + attn@V -> out_pre (bf16)
  softav_k<<<dim3(256, 2), 256, 0, stream>>>(S, v_t, c_seq, c_lex, out_pre);

  // 7) final: out = out_pre @ Wo.T + bo -> d_out (dtype per flag)
  GArgs gC = {};
  gC.d[0] = {out_pre, canon[14], canon[15], d_out, 512, 512, 512, 512, 512, 0, 512, 2, 0, 0};
  gemm2_k<<<dim3(8, 8, 1), 256, 0, stream>>>(gC, flags);
}

// Round 13
// 216.852 us; speedup vs baseline: 2.9988x; 1.0291x over previous
//
#include <hip/hip_runtime.h>
#include <hip/hip_bf16.h>

typedef unsigned short USHORT;
typedef long long LL;
typedef short s8v __attribute__((ext_vector_type(8)));
typedef float f32x4 __attribute__((ext_vector_type(4)));

// B=2, L=256, H=512, NH=8, DH=64, MAXLEN=256, PE_ROWS=513
// Dtypes runtime-detected: floats f32-or-bf16 (canonicalized bf16), ints i32-or-i64.
// R13: score+softmax+attnV fused into one 1024-thread kernel (att lives in LDS);
// S buffer now holds only S_AC. 6 dispatches.

__device__ __forceinline__ float bf2f(USHORT u) {
  union { unsigned int i; float f; } v; v.i = ((unsigned int)u) << 16; return v.f;
}
__device__ __forceinline__ USHORT f2bf(float f) {
  unsigned int x = __float_as_uint(f);
  return (USHORT)((x + 0x7fffu + ((x >> 16) & 1u)) >> 16);
}

// ---------------- prep: dtype-detect + canonicalize + WrT + ints + flags ----------------
struct PrepArgs {
  const void* fsrc[18]; USHORT* fdst[18]; int fn[18];
  const void* wr_src; USHORT* wrT;
  const void* isrc[4]; int* idst[4];
};

__global__ __launch_bounds__(256) void prep_k(PrepArgs a, const void* qraw, int* flags) {
  __shared__ int s_w;
  const int t = threadIdx.x;
  if (t == 0) s_w = 0;
  __syncthreads();
  const USHORT* qb = (const USHORT*)qraw;
  int wild = 0;
  for (int c = t; c < 512; c += 256) {
    float x = bf2f(qb[c]);
    if (!(fabsf(x) <= 1024.0f)) wild = 1;  // catches NaN too
  }
  if (wild) atomicAdd(&s_w, 1);
  __syncthreads();
  const int f = (s_w == 0) ? 1 : 0;  // 1 iff float inputs are bf16

  const int y = blockIdx.y;
  if (y < 18) {
    const int n = a.fn[y];
    const USHORT* sb = (const USHORT*)a.fsrc[y];
    const float* sf = (const float*)a.fsrc[y];
    USHORT* d = a.fdst[y];
    for (int idx = blockIdx.x * 256 + t; idx < n; idx += gridDim.x * 256)
      d[idx] = f ? sb[idx] : f2bf(sf[idx]);
  } else if (y == 18) {
    const USHORT* sb = (const USHORT*)a.wr_src;
    const float* sf = (const float*)a.wr_src;
    for (int idx = blockIdx.x * 256 + t; idx < 262144; idx += gridDim.x * 256) {
      const int e = idx >> 9, dd = idx & 511;
      const int s = dd * 512 + e;
      a.wrT[idx] = f ? sb[s] : f2bf(sf[s]);  // WrT[e][d] = Wr[d][e]
    }
  } else if (blockIdx.x == 0) {
    if (t == 0) flags[0] = f;
    const int fi = (((const int*)a.isrc[0])[1] == 0) ? 1 : 0;  // seq_len[0] in [100,200)
    if (t < 2) {
      a.idst[0][t] = fi ? (int)((const LL*)a.isrc[0])[t] : ((const int*)a.isrc[0])[t];
      a.idst[1][t] = fi ? (int)((const LL*)a.isrc[1])[t] : ((const int*)a.isrc[1])[t];
    }
    for (int c = t; c < 512; c += 256) {
      a.idst[2][c] = fi ? (int)((const LL*)a.isrc[2])[c] : ((const int*)a.isrc[2])[c];
      a.idst[3][c] = fi ? (int)((const LL*)a.isrc[3])[c] : ((const int*)a.isrc[3])[c];
    }
  }
}

// ---------------- generic multi-desc MFMA GEMM (R7-proven) ----------------
struct GDesc {
  const USHORT* A; const USHORT* W; const USHORT* bias;
  void* out;
  int M, N, K, lda, ldw, koff, ldo, mode, trans, pad;  // mode: 0 f32, 1 bf16, 2 per-flag
};
struct GArgs { GDesc d[32]; };

__global__ __launch_bounds__(256) void gemm2_k(GArgs ga, const int* __restrict__ flags) {
  const GDesc de = ga.d[blockIdx.z];
  const int row0 = blockIdx.y * 64, col0 = blockIdx.x * 64;
  if (row0 >= de.M || col0 >= de.N) return;
  const int wave = threadIdx.x >> 6, lane = threadIdx.x & 63;
  const int mrow = row0 + wave * 16 + (lane & 15);
  const int kq = (lane >> 4) * 8;
  const bool mok = (mrow < de.M);
  const USHORT* ar = de.A + (long)(mok ? mrow : row0) * de.lda + kq;
  const int nc = col0 + (lane & 15);
  const USHORT* w0p = de.W + (long)(nc +  0) * de.ldw + de.koff + kq;
  const USHORT* w1p = de.W + (long)(nc + 16) * de.ldw + de.koff + kq;
  const USHORT* w2p = de.W + (long)(nc + 32) * de.ldw + de.koff + kq;
  const USHORT* w3p = de.W + (long)(nc + 48) * de.ldw + de.koff + kq;

  f32x4 acc[4] = {};
#pragma unroll 4
  for (int k0 = 0; k0 < de.K; k0 += 32) {
    s8v a = *(const s8v*)(ar + k0);
    s8v wv0 = *(const s8v*)(w0p + k0);
    s8v wv1 = *(const s8v*)(w1p + k0);
    s8v wv2 = *(const s8v*)(w2p + k0);
    s8v wv3 = *(const s8v*)(w3p + k0);
    acc[0] = __builtin_amdgcn_mfma_f32_16x16x32_bf16(a, wv0, acc[0], 0, 0, 0);
    acc[1] = __builtin_amdgcn_mfma_f32_16x16x32_bf16(a, wv1, acc[1], 0, 0, 0);
    acc[2] = __builtin_amdgcn_mfma_f32_16x16x32_bf16(a, wv2, acc[2], 0, 0, 0);
    acc[3] = __builtin_amdgcn_mfma_f32_16x16x32_bf16(a, wv3, acc[3], 0, 0, 0);
  }

  const int obf = (de.mode == 2) ? flags[0] : (de.mode == 1);
  const int mbase = row0 + wave * 16 + (lane >> 4) * 4;
#pragma unroll
  for (int nt = 0; nt < 4; nt++) {
    const int n = col0 + nt * 16 + (lane & 15);
    const float bias = de.bias ? bf2f(de.bias[n]) : 0.f;
#pragma unroll
    for (int r = 0; r < 4; r++) {
      const int m = mbase + r;
      if (m >= de.M) continue;
      const float vo = acc[nt][r] + bias;
      const long off = de.trans ? ((long)n * de.ldo + m) : ((long)m * de.ldo + n);
      if (obf) ((USHORT*)de.out)[off] = f2bf(vo);
      else     ((float*)de.out)[off] = vo;
    }
  }
}

// ---------------- mid: full relu T-table + cbv + uk + vwr ----------------
__global__ __launch_bounds__(256) void mid_k(
    const USHORT* __restrict__ Ptab, const USHORT* __restrict__ q_n,
    const USHORT* __restrict__ k_n, const USHORT* __restrict__ WrT,
    const USHORT* __restrict__ u_bf, const USHORT* __restrict__ v_bf,
    const USHORT* __restrict__ br_bf,
    USHORT* __restrict__ T,
    float* __restrict__ cbv, float* __restrict__ uk, USHORT* __restrict__ vwr)
{
  const int bid = blockIdx.x, t = threadIdx.x, gsz = gridDim.x;
  const long TS = 513l * 512;
  for (int r = bid; r < 12825; r += gsz) {
    const int S0 = r / 25, rem = r % 25, di = rem / 5, dj = rem % 5;
    const USHORT* p1 = Ptab + (long)S0 * 512;
    const USHORT* p2 = Ptab + TS + (long)max(S0 - dj, 0) * 512;
    const USHORT* p3 = Ptab + 2 * TS + (long)min(S0 + di, 512) * 512;
    const USHORT* p4 = Ptab + 3 * TS + (long)min(max(S0 + di - dj, 0), 512) * 512;
    USHORT* to = T + (long)r * 512;
    const int e = t * 2;
    ushort2 x1 = *(const ushort2*)(p1 + e);
    ushort2 x2 = *(const ushort2*)(p2 + e);
    ushort2 x3 = *(const ushort2*)(p3 + e);
    ushort2 x4 = *(const ushort2*)(p4 + e);
    ushort2 o;
    o.x = f2bf(fmaxf(bf2f(x1.x) + bf2f(x2.x) + bf2f(x3.x) + bf2f(x4.x), 0.f));
    o.y = f2bf(fmaxf(bf2f(x1.y) + bf2f(x2.y) + bf2f(x3.y) + bf2f(x4.y), 0.f));
    *(ushort2*)(to + e) = o;
  }
  for (int idx = bid * 256 + t; idx < 262144; idx += gsz * 256) {
    const int hd = idx & 511;
    float s = (bf2f(q_n[idx]) + bf2f(v_bf[hd])) * bf2f(br_bf[hd]);
    float s2 = bf2f(k_n[idx]) * bf2f(u_bf[hd]);
#pragma unroll
    for (int off = 32; off > 0; off >>= 1) { s += __shfl_xor(s, off); s2 += __shfl_xor(s2, off); }
    if ((t & 63) == 0) { cbv[idx >> 6] = s; uk[idx >> 6] = s2; }
  }
  for (int o = bid * 256 + t; o < 4096; o += gsz * 256) {
    const int h = o >> 9, e = o & 511;
    float s = 0.f;
    const USHORT* wrow = WrT + (long)e * 512 + h * 64;
    const USHORT* vrow = v_bf + h * 64;
#pragma unroll
    for (int d = 0; d < 64; d += 4) {
      ushort4 wv = *(const ushort4*)(wrow + d);
      ushort4 vv = *(const ushort4*)(vrow + d);
      s += bf2f(vv.x) * bf2f(wv.x) + bf2f(vv.y) * bf2f(wv.y) +
           bf2f(vv.z) * bf2f(wv.z) + bf2f(vv.w) * bf2f(wv.w);
    }
    vwr[o] = f2bf(s);  // vwr[h*512+e]
  }
}

// ---------------- fused score + softmax + attn@V: one block per (b,i), 16 waves -------
// Wave w = j-tile w (exhaustive 0..15). att in LDS; softmax via 4x256-thread subgroups;
// AV from LDS (threads < 512, one (h,d) each).
__global__ __launch_bounds__(1024) void score6_k(
    const USHORT* __restrict__ T,
    const float* __restrict__ cbv, const float* __restrict__ uk,
    const USHORT* __restrict__ wbuf, const float* __restrict__ S_AC,
    const USHORT* __restrict__ v_t,
    const int* __restrict__ seq_len, const int* __restrict__ lex_num,
    const int* __restrict__ pos_s, const int* __restrict__ pos_e,
    USHORT* __restrict__ out_pre)
{
  __shared__ float att[8 * 256];
  __shared__ float red[4][4];
  const int i = blockIdx.x, b = blockIdx.y, t = threadIdx.x;
  const int wave = t >> 6, lane = t & 63;
  int tl = seq_len[b] + lex_num[b];
  tl = min(max(tl, 1), 256);

  const int j0 = wave * 16;
  if (j0 < tl) {
    const int n = lane & 15, q = lane >> 4;
    const int psi = pos_s[b * 256 + i], pei = pos_e[b * 256 + i];
    const int j = j0 + n;
    const int psj = pos_s[b * 256 + j], pej = pos_e[b * 256 + j];
    const int S0 = min(max(psi - psj + 256, 0), 512);
    const int di = min(max(pei - psi, 0), 4);
    const int dj = min(max(pej - psj, 0), 4);
    const USHORT* tp = T + ((long)(S0 * 25 + di * 5 + dj)) * 512 + q * 8;
    const USHORT* wr = wbuf + ((long)((b * 8 + (n & 7)) * 256 + i)) * 512 + q * 8;
    f32x4 acc = {0.f, 0.f, 0.f, 0.f};
#pragma unroll
    for (int kk = 0; kk < 16; kk++) {
      s8v av = *(const s8v*)(tp + kk * 32);
      s8v wv = *(const s8v*)(wr + kk * 32);  // n>=8 duplicates h=n-8; D cols discarded
      acc = __builtin_amdgcn_mfma_f32_16x16x32_bf16(av, wv, acc, 0, 0, 0);
    }
    if (n < 8) {  // D: col h = lane&15, row j_local = q*4+r
      const long base = (long)(b * 8 + n) * 256 + i;
      const float cb = cbv[(long)(b * 256 + i) * 8 + n];
      const float4 sac = *(const float4*)(S_AC + base * 256 + j0 + q * 4);
      const float* sacp = (const float*)&sac;
#pragma unroll
      for (int r = 0; r < 4; r++) {
        const int jr = j0 + q * 4 + r;
        att[n * 256 + jr] = (acc[r] + sacp[r] + cb + uk[(long)(b * 256 + jr) * 8 + n]) * 0.125f;
      }
    }
  }
  __syncthreads();

  // softmax: subgroup hg (256 thr) handles heads hg and hg+4
  const int hg = t >> 8, tj = t & 255, wig = wave & 3;
#pragma unroll
  for (int hh = 0; hh < 2; hh++) {
    const int h = hg + 4 * hh;
    const float val = (tj < tl) ? att[h * 256 + tj] : -3.0e38f;
    float m = val;
#pragma unroll
    for (int off = 32; off > 0; off >>= 1) m = fmaxf(m, __shfl_xor(m, off));
    if (lane == 0) red[hg][wig] = m;
    __syncthreads();
    m = fmaxf(fmaxf(red[hg][0], red[hg][1]), fmaxf(red[hg][2], red[hg][3]));
    const float pv = (tj < tl) ? __expf(val - m) : 0.f;
    float s = pv;
#pragma unroll
    for (int off = 32; off > 0; off >>= 1) s += __shfl_xor(s, off);
    __syncthreads();
    if (lane == 0) red[hg][wig] = s;
    __syncthreads();
    s = red[hg][0] + red[hg][1] + red[hg][2] + red[hg][3];
    if (!(s > 1e-30f)) s = 1.f;
    att[h * 256 + tj] = pv / s;  // all 256 j written: masked tail becomes exact 0
    __syncthreads();
  }

  // attn @ V: threads < 512, one (h,d) each; att rows broadcast from LDS
  if (t < 512) {
    const int h = t >> 6, d = t & 63;
    const USHORT* vrow = v_t + (long)(h * 64 + d) * 512 + b * 256;
    const float* arow = &att[h * 256];
    float acc = 0.f;
    const int tl4 = (tl + 3) & ~3;
    for (int jj = 0; jj < tl4; jj += 4) {
      ushort4 vv = *(const ushort4*)(vrow + jj);
      acc += arow[jj + 0] * bf2f(vv.x) + arow[jj + 1] * bf2f(vv.y) +
             arow[jj + 2] * bf2f(vv.z) + arow[jj + 3] * bf2f(vv.w);
    }
    out_pre[(long)(b * 256 + i) * 512 + h * 64 + d] = f2bf(acc);
  }
}

extern "C" void kernel_launch(void* const* d_in, const int* in_sizes, int n_in,
                              void* d_out, int out_size, void* d_ws, size_t ws_size,
                              hipStream_t stream) {
  (void)in_sizes; (void)n_in; (void)out_size; (void)ws_size;

  char* w = (char*)d_ws;
  auto take = [&](size_t n) { char* r = w; w += (n + 255) & ~(size_t)255; return r; };

  int* flags   = (int*)take(16);
  int* c_seq   = (int*)take(16);
  int* c_lex   = (int*)take(16);
  int* c_pos_s = (int*)take(2048);
  int* c_pos_e = (int*)take(2048);
  const int ns[18] = {262144,262144,262144,262656,1048576,512,262144,512,262144,512,
                      262144,512,262144,512,262144,512,512,512};
  USHORT* canon[18];
  for (int i = 0; i < 18; i++) canon[i] = (USHORT*)take((size_t)ns[i] * 2);
  USHORT* WrT     = (USHORT*)take((size_t)262144 * 2);
  USHORT* q_n     = (USHORT*)take((size_t)262144 * 2);
  USHORT* k_n     = (USHORT*)take((size_t)262144 * 2);
  USHORT* v_t     = (USHORT*)take((size_t)262144 * 2);
  USHORT* wbuf    = (USHORT*)take((size_t)2097152 * 2);
  USHORT* Ptab    = (USHORT*)take((size_t)1050624 * 2);
  USHORT* T       = (USHORT*)take((size_t)12825 * 512 * 2);
  USHORT* vwr     = (USHORT*)take((size_t)4096 * 2);
  USHORT* out_pre = (USHORT*)take((size_t)262144 * 2);
  float* S   = (float*)take((size_t)1048576 * 4);   // S_AC only
  float* cbv = (float*)take((size_t)4096 * 4);
  float* uk  = (float*)take((size_t)4096 * 4);

  // 1) prep
  PrepArgs pa;
  for (int i = 0; i < 18; i++) { pa.fsrc[i] = d_in[i]; pa.fdst[i] = canon[i]; pa.fn[i] = ns[i]; }
  pa.wr_src = d_in[12]; pa.wrT = WrT;
  for (int i = 0; i < 4; i++) pa.isrc[i] = d_in[18 + i];
  pa.idst[0] = c_seq; pa.idst[1] = c_lex; pa.idst[2] = c_pos_s; pa.idst[3] = c_pos_e;
  prep_k<<<dim3(64, 20), 256, 0, stream>>>(pa, d_in[1], flags);

  // 2) g1: P tables (bf16, +bf in tbl0) + q/k (bf16) + v (bf16, transposed)
  GArgs gA = {};
  for (int z = 0; z < 4; z++)
    gA.d[z] = {canon[3], canon[4], (z == 0) ? canon[5] : nullptr, Ptab + (long)z * 513 * 512,
               513, 512, 512, 512, 2048, z * 512, 512, 1, 0, 0};
  gA.d[4] = {canon[1], canon[8],  canon[9],  q_n, 512, 512, 512, 512, 512, 0, 512, 1, 0, 0};
  gA.d[5] = {canon[0], canon[6],  canon[7],  k_n, 512, 512, 512, 512, 512, 0, 512, 1, 0, 0};
  gA.d[6] = {canon[2], canon[10], canon[11], v_t, 512, 512, 512, 512, 512, 0, 512, 1, 1, 0};
  gemm2_k<<<dim3(8, 9, 7), 256, 0, stream>>>(gA, flags);

  // 3) mid: T table + cbv + uk + vwr
  mid_k<<<512, 256, 0, stream>>>(Ptab, q_n, k_n, WrT, canon[16], canon[17], canon[13],
                                 T, cbv, uk, vwr);

  // 4) g2: wproj (q@WrT + vwr bias, bf16) + S_AC (q@k^T, f32 into S)
  GArgs gB = {};
  for (int z = 0; z < 16; z++) {
    const int b = z >> 3, h = z & 7;
    gB.d[z] = {q_n + b * 131072 + h * 64, WrT, vwr + h * 512, wbuf + (long)z * 131072,
               256, 512, 64, 512, 512, h * 64, 512, 1, 0, 0};
  }
  for (int z = 0; z < 16; z++) {
    const int b = z >> 3, h = z & 7;
    gB.d[16 + z] = {q_n + b * 131072 + h * 64, k_n + b * 131072 + h * 64, nullptr,
                    S + (long)z * 65536, 256, 256, 64, 512, 512, 0, 256, 0, 0, 0};
  }
  gemm2_k<<<dim3(8, 4, 32), 256, 0, stream>>>(gB, flags);

  // 5) fused score + softmax + attn@V -> out_pre (bf16)
  score6_k<<<dim3(256, 2), 1024, 0, stream>>>(
      T, cbv, uk, wbuf, S, v_t, c_seq, c_lex, c_pos_s, c_pos_e, out_pre);

  // 6) final: out = out_pre @ Wo.T + bo -> d_out (dtype per flag)
  GArgs gC = {};
  gC.d[0] = {out_pre, canon[14], canon[15], d_out, 512, 512, 512, 512, 512, 0, 512, 2, 0, 0};
  gemm2_k<<<dim3(8, 8, 1), 256, 0, stream>>>(gC, flags);
}